// Round 1
// baseline (183.896 us; speedup 1.0000x reference)
//
#include <hip/hip_runtime.h>
#include <stdint.h>
#include <stddef.h>

#define S_LEN 2048
#define NH 16
#define HD 64          // head dim
#define DM 1024        // model dim
#define NQKV 3072      // 3*DM
#define MROWS 4096     // B*S
#define NBH 32         // B*NH

typedef float f32x4 __attribute__((ext_vector_type(4)));
typedef __bf16 bf16x8 __attribute__((ext_vector_type(8)));
typedef short short8_t __attribute__((ext_vector_type(8)));

// round-to-nearest-even fp32 -> bf16 (inputs finite)
__device__ __forceinline__ unsigned short f2bf(float f) {
  union { float f; unsigned int u; } v; v.f = f;
  unsigned int u = v.u;
  u += 0x7FFFu + ((u >> 16) & 1u);
  return (unsigned short)(u >> 16);
}

// async global->LDS, 16B per lane. LDS dest must be (wave-uniform base + lane*16).
__device__ __forceinline__ void async_copy16(const void* g, void* l) {
  __builtin_amdgcn_global_load_lds(
      (const __attribute__((address_space(1))) void*)g,
      (__attribute__((address_space(3))) void*)l, 16, 0, 0);
}

// ---------------- precast x -> bf16 ----------------
__global__ __launch_bounds__(256) void cast_x_kernel(const float* __restrict__ x,
                                                     unsigned short* __restrict__ xb) {
  size_t i = ((size_t)blockIdx.x * 256 + threadIdx.x) * 8;
  f32x4 a = *(const f32x4*)(x + i);
  f32x4 b = *(const f32x4*)(x + i + 4);
  union { unsigned short u[8]; short8_t v; } o;
  o.u[0] = f2bf(a[0]); o.u[1] = f2bf(a[1]); o.u[2] = f2bf(a[2]); o.u[3] = f2bf(a[3]);
  o.u[4] = f2bf(b[0]); o.u[5] = f2bf(b[1]); o.u[6] = f2bf(b[2]); o.u[7] = f2bf(b[3]);
  *(short8_t*)(xb + i) = o.v;
}

// ---------------- W[K][N] -> Wt[N][K] bf16 (LDS tile transpose) ----------------
__global__ __launch_bounds__(256) void transpose_w_kernel(const float* __restrict__ W,
                                                          unsigned short* __restrict__ wt) {
  __shared__ float tile[32][33];
  const int n0 = blockIdx.x * 32;
  const int k0 = blockIdx.y * 32;
  const int tx = threadIdx.x;   // 0..31
  const int ty = threadIdx.y;   // 0..7
  #pragma unroll
  for (int i = 0; i < 4; ++i)
    tile[ty + i * 8][tx] = W[(size_t)(k0 + ty + i * 8) * NQKV + n0 + tx];
  __syncthreads();
  #pragma unroll
  for (int i = 0; i < 4; ++i)
    wt[(size_t)(n0 + ty + i * 8) * DM + k0 + tx] = f2bf(tile[tx][ty + i * 8]);
}

// ---------------- QKV GEMM: [4096,1024] x [1024,3072] + bias -> Q,K,V^T (bf16) ----------------
// 128x128 tile, BK=64, 4 waves (2x2), 16x16x32 bf16 MFMA, global_load_lds staging
// with pre-swizzled source so LDS reads (^((row&7)<<4)) are bank-conflict-free.
__global__ __launch_bounds__(256) void qkv_gemm_kernel(
    const unsigned short* __restrict__ xb, const unsigned short* __restrict__ wt,
    const float* __restrict__ bias,
    unsigned short* __restrict__ Qb, unsigned short* __restrict__ Kb,
    unsigned short* __restrict__ Vt) {
  __shared__ __align__(16) unsigned char As[128 * 128];  // 128 rows x 64 bf16
  __shared__ __align__(16) unsigned char Bs[128 * 128];
  const int t = threadIdx.x;
  const int lane = t & 63;
  const int wave = t >> 6;
  const int wm = (wave >> 1) * 64, wn = (wave & 1) * 64;
  const int lr = lane & 15, g = lane >> 4;
  const int m0 = blockIdx.x * 128, n0 = blockIdx.y * 128;

  f32x4 acc[4][4];
  #pragma unroll
  for (int i = 0; i < 4; ++i)
    #pragma unroll
    for (int j = 0; j < 4; ++j) acc[i][j] = f32x4{0.f, 0.f, 0.f, 0.f};

  for (int k0 = 0; k0 < DM; k0 += 64) {
    __syncthreads();
    #pragma unroll
    for (int i = 0; i < 4; ++i) {
      int c = t + i * 256;            // 1024 chunks of 16B per tile
      int row = c >> 3;               // 0..127
      int cc = (c & 7) ^ (row & 7);   // inverse swizzle on the GLOBAL side
      async_copy16(xb + (size_t)(m0 + row) * DM + k0 + cc * 8, As + c * 16);
      async_copy16(wt + (size_t)(n0 + row) * DM + k0 + cc * 8, Bs + c * 16);
    }
    __syncthreads();  // barrier drains vmcnt -> tiles ready

    bf16x8 af[2][4], bfr[2][4];
    #pragma unroll
    for (int kk = 0; kk < 2; ++kk) {
      #pragma unroll
      for (int i = 0; i < 4; ++i) {
        int ra = wm + i * 16 + lr;
        af[kk][i] = *(const bf16x8*)(As + ((ra * 128 + kk * 64 + g * 16) ^ ((ra & 7) << 4)));
        int rb = wn + i * 16 + lr;
        bfr[kk][i] = *(const bf16x8*)(Bs + ((rb * 128 + kk * 64 + g * 16) ^ ((rb & 7) << 4)));
      }
    }
    #pragma unroll
    for (int kk = 0; kk < 2; ++kk)
      #pragma unroll
      for (int mi = 0; mi < 4; ++mi)
        #pragma unroll
        for (int ni = 0; ni < 4; ++ni)
          acc[mi][ni] = __builtin_amdgcn_mfma_f32_16x16x32_bf16(
              af[kk][mi], bfr[kk][ni], acc[mi][ni], 0, 0, 0);
  }

  // epilogue: +bias, route column n -> (head, q/k/v, d); V stored transposed [bh][d][s]
  #pragma unroll
  for (int ni = 0; ni < 4; ++ni) {
    int n = n0 + wn + ni * 16 + lr;
    float bv = bias[n];
    int h = n / 192;
    int rr = n % 192;
    int typ = rr >> 6;
    int d = rr & 63;
    #pragma unroll
    for (int mi = 0; mi < 4; ++mi) {
      #pragma unroll
      for (int r = 0; r < 4; ++r) {
        int m = m0 + wm + mi * 16 + g * 4 + r;   // C row = (lane>>4)*4+reg (verified layout)
        int b = m >> 11, s = m & 2047;
        int bh = b * NH + h;
        unsigned short val = f2bf(acc[mi][ni][r] + bv);
        if (typ == 0)      Qb[((size_t)bh * S_LEN + s) * HD + d] = val;
        else if (typ == 1) Kb[((size_t)bh * S_LEN + s) * HD + d] = val;
        else               Vt[((size_t)bh * HD + d) * S_LEN + s] = val;
      }
    }
  }
}

// ---------------- flash attention: 32 bh x 32 q-tiles, 4 waves x 16 q-rows ----------------
__global__ __launch_bounds__(256) void attn_kernel(
    const unsigned short* __restrict__ Qb, const unsigned short* __restrict__ Kb,
    const unsigned short* __restrict__ Vt, float* __restrict__ out) {
  __shared__ __align__(16) unsigned char Ks[64 * 128];      // K tile [64 keys][64 d]
  __shared__ __align__(16) unsigned char Vs[64 * 128];      // V^T tile [64 d][64 j]
  __shared__ __align__(16) unsigned char Ps[4][16 * 128];   // per-wave P [16 q][64 j]
  const int t = threadIdx.x;
  const int lane = t & 63;
  const int wave = t >> 6;
  const int lr = lane & 15, g = lane >> 4;
  const int bh = blockIdx.y;
  const int q0 = blockIdx.x * 64 + wave * 16;

  const unsigned short* Qbh = Qb + (size_t)bh * S_LEN * HD;
  const unsigned short* Kbh = Kb + (size_t)bh * S_LEN * HD;
  const unsigned short* Vbh = Vt + (size_t)bh * HD * S_LEN;

  bf16x8 qf[2];  // Q fragment held in registers for the whole loop
  #pragma unroll
  for (int kk = 0; kk < 2; ++kk)
    qf[kk] = *(const bf16x8*)(Qbh + (size_t)(q0 + lr) * HD + kk * 32 + g * 8);

  const float SC = 0.125f * 1.4426950408889634f;  // 1/sqrt(64) * log2(e)
  float m2[4], lsum[4];
  f32x4 oacc[4];
  #pragma unroll
  for (int r = 0; r < 4; ++r) { m2[r] = -1e30f; lsum[r] = 0.f; }
  #pragma unroll
  for (int di = 0; di < 4; ++di) oacc[di] = f32x4{0.f, 0.f, 0.f, 0.f};

  for (int kv = 0; kv < S_LEN; kv += 64) {
    __syncthreads();  // previous tile's reads done
    #pragma unroll
    for (int i = 0; i < 2; ++i) {
      int c = t + i * 256;            // 512 chunks per tile
      int row = c >> 3;               // 0..63
      int cc = (c & 7) ^ (row & 7);
      async_copy16(Kbh + (size_t)(kv + row) * HD + cc * 8, Ks + c * 16);
      async_copy16(Vbh + (size_t)row * S_LEN + kv + cc * 8, Vs + c * 16);
    }
    __syncthreads();  // drains vmcnt -> K/V ready

    // S = Q K^T  (16 q x 64 keys per wave)
    f32x4 sacc[4];
    #pragma unroll
    for (int ni = 0; ni < 4; ++ni) {
      sacc[ni] = f32x4{0.f, 0.f, 0.f, 0.f};
      #pragma unroll
      for (int kk = 0; kk < 2; ++kk) {
        int r = ni * 16 + lr;
        bf16x8 kf = *(const bf16x8*)(Ks + ((r * 128 + kk * 64 + g * 16) ^ ((r & 7) << 4)));
        sacc[ni] = __builtin_amdgcn_mfma_f32_16x16x32_bf16(qf[kk], kf, sacc[ni], 0, 0, 0);
      }
    }

    // online softmax (exp2 domain); C layout: col=lane&15 (key), row=g*4+reg (q)
    unsigned char* Pw = Ps[wave];
    #pragma unroll
    for (int r = 0; r < 4; ++r) {
      float tm = fmaxf(fmaxf(sacc[0][r], sacc[1][r]), fmaxf(sacc[2][r], sacc[3][r])) * SC;
      tm = fmaxf(tm, __shfl_xor(tm, 1));
      tm = fmaxf(tm, __shfl_xor(tm, 2));
      tm = fmaxf(tm, __shfl_xor(tm, 4));
      tm = fmaxf(tm, __shfl_xor(tm, 8));
      float mn = fmaxf(m2[r], tm);
      float alpha = exp2f(m2[r] - mn);
      m2[r] = mn;
      int q = g * 4 + r;
      float ps = 0.f;
      #pragma unroll
      for (int ni = 0; ni < 4; ++ni) {
        float pv = exp2f(sacc[ni][r] * SC - mn);
        ps += pv;
        int byte = (q * 128 + (ni * 16 + lr) * 2) ^ ((q & 7) << 4);
        *(unsigned short*)(Pw + byte) = f2bf(pv);
      }
      ps += __shfl_xor(ps, 1);
      ps += __shfl_xor(ps, 2);
      ps += __shfl_xor(ps, 4);
      ps += __shfl_xor(ps, 8);
      lsum[r] = lsum[r] * alpha + ps;
      #pragma unroll
      for (int di = 0; di < 4; ++di) oacc[di][r] *= alpha;
    }

    // wave-local drain of the P ds_writes before reading them back
    asm volatile("s_waitcnt lgkmcnt(0)" ::: "memory");
    __builtin_amdgcn_sched_barrier(0);

    // O += P V   (A = P[16 q][64 j], B = V^T[d][j])
    bf16x8 pf[2];
    #pragma unroll
    for (int kk = 0; kk < 2; ++kk)
      pf[kk] = *(const bf16x8*)(Pw + ((lr * 128 + kk * 64 + g * 16) ^ ((lr & 7) << 4)));
    #pragma unroll
    for (int di = 0; di < 4; ++di) {
      #pragma unroll
      for (int kk = 0; kk < 2; ++kk) {
        int r = di * 16 + lr;
        bf16x8 vf = *(const bf16x8*)(Vs + ((r * 128 + kk * 64 + g * 16) ^ ((r & 7) << 4)));
        oacc[di] = __builtin_amdgcn_mfma_f32_16x16x32_bf16(pf[kk], vf, oacc[di], 0, 0, 0);
      }
    }
  }

  // normalize + write: out flat layout is [b][h][q][d] (reference's raw reshape)
  float* outp = out + ((size_t)bh * S_LEN + q0) * HD;
  #pragma unroll
  for (int r = 0; r < 4; ++r) {
    float inv = 1.0f / lsum[r];
    int q = g * 4 + r;
    #pragma unroll
    for (int di = 0; di < 4; ++di)
      outp[q * HD + di * 16 + lr] = oacc[di][r] * inv;
  }
}

extern "C" void kernel_launch(void* const* d_in, const int* in_sizes, int n_in,
                              void* d_out, int out_size, void* d_ws, size_t ws_size,
                              hipStream_t stream) {
  const float* x    = (const float*)d_in[0];
  const float* W    = (const float*)d_in[1];
  const float* bias = (const float*)d_in[2];
  float* out = (float*)d_out;

  // workspace partition (bf16 everywhere): ~38 MB total
  unsigned short* xb = (unsigned short*)d_ws;
  unsigned short* wt = xb + (size_t)MROWS * DM;
  unsigned short* Qb = wt + (size_t)NQKV * DM;
  unsigned short* Kb = Qb + (size_t)NBH * S_LEN * HD;
  unsigned short* Vt = Kb + (size_t)NBH * S_LEN * HD;

  cast_x_kernel<<<(MROWS * DM) / (256 * 8), 256, 0, stream>>>(x, xb);
  transpose_w_kernel<<<dim3(NQKV / 32, DM / 32), dim3(32, 8), 0, stream>>>(W, wt);
  qkv_gemm_kernel<<<dim3(MROWS / 128, NQKV / 128), 256, 0, stream>>>(xb, wt, bias, Qb, Kb, Vt);
  attn_kernel<<<dim3(S_LEN / 64, NBH), 256, 0, stream>>>(Qb, Kb, Vt, out);
}

// Round 2
// 167.921 us; speedup vs baseline: 1.0951x; 1.0951x over previous
//
#include <hip/hip_runtime.h>
#include <stdint.h>
#include <stddef.h>

#define S_LEN 2048
#define NH 16
#define HD 64          // head dim
#define DM 1024        // model dim
#define NQKV 3072      // 3*DM
#define MROWS 4096     // B*S
#define NBH 32         // B*NH

typedef float f32x4 __attribute__((ext_vector_type(4)));
typedef __bf16 bf16x8 __attribute__((ext_vector_type(8)));
typedef short short8_t __attribute__((ext_vector_type(8)));
typedef unsigned int u32x2 __attribute__((ext_vector_type(2)));

// round-to-nearest-even fp32 -> bf16 (inputs finite)
__device__ __forceinline__ unsigned short f2bf(float f) {
  union { float f; unsigned int u; } v; v.f = f;
  unsigned int u = v.u;
  u += 0x7FFFu + ((u >> 16) & 1u);
  return (unsigned short)(u >> 16);
}

// async global->LDS, 16B per lane. LDS dest must be (wave-uniform base + lane*16).
__device__ __forceinline__ void async_copy16(const void* g, void* l) {
  __builtin_amdgcn_global_load_lds(
      (const __attribute__((address_space(1))) void*)g,
      (__attribute__((address_space(3))) void*)l, 16, 0, 0);
}

// ---------------- precast x -> bf16 ----------------
__global__ __launch_bounds__(256) void cast_x_kernel(const float* __restrict__ x,
                                                     unsigned short* __restrict__ xb) {
  size_t i = ((size_t)blockIdx.x * 256 + threadIdx.x) * 8;
  f32x4 a = *(const f32x4*)(x + i);
  f32x4 b = *(const f32x4*)(x + i + 4);
  union { unsigned short u[8]; short8_t v; } o;
  o.u[0] = f2bf(a[0]); o.u[1] = f2bf(a[1]); o.u[2] = f2bf(a[2]); o.u[3] = f2bf(a[3]);
  o.u[4] = f2bf(b[0]); o.u[5] = f2bf(b[1]); o.u[6] = f2bf(b[2]); o.u[7] = f2bf(b[3]);
  *(short8_t*)(xb + i) = o.v;
}

// ---------------- W[K][N] -> Wt[N][K] bf16 (LDS tile transpose) ----------------
__global__ __launch_bounds__(256) void transpose_w_kernel(const float* __restrict__ W,
                                                          unsigned short* __restrict__ wt) {
  __shared__ float tile[32][33];
  const int n0 = blockIdx.x * 32;
  const int k0 = blockIdx.y * 32;
  const int tx = threadIdx.x;   // 0..31
  const int ty = threadIdx.y;   // 0..7
  #pragma unroll
  for (int i = 0; i < 4; ++i)
    tile[ty + i * 8][tx] = W[(size_t)(k0 + ty + i * 8) * NQKV + n0 + tx];
  __syncthreads();
  #pragma unroll
  for (int i = 0; i < 4; ++i)
    wt[(size_t)(n0 + ty + i * 8) * DM + k0 + tx] = f2bf(tile[tx][ty + i * 8]);
}

// ---------------- QKV GEMM: [4096,1024] x [1024,3072] + bias -> Q,K,V^T (bf16) ----------------
// 128x128 tile, BK=64, 4 waves (2x2), 16x16x32 bf16 MFMA, global_load_lds staging
// with pre-swizzled source so LDS reads (^((row&7)<<4)) are bank-conflict-free.
// Q is pre-scaled by 1/sqrt(64)*log2(e) so attention works in exp2 domain directly.
__global__ __launch_bounds__(256) void qkv_gemm_kernel(
    const unsigned short* __restrict__ xb, const unsigned short* __restrict__ wt,
    const float* __restrict__ bias,
    unsigned short* __restrict__ Qb, unsigned short* __restrict__ Kb,
    unsigned short* __restrict__ Vt) {
  __shared__ __align__(16) unsigned char As[128 * 128];  // 128 rows x 64 bf16
  __shared__ __align__(16) unsigned char Bs[128 * 128];
  const int t = threadIdx.x;
  const int lane = t & 63;
  const int wave = t >> 6;
  const int wm = (wave >> 1) * 64, wn = (wave & 1) * 64;
  const int lr = lane & 15, g = lane >> 4;
  const int m0 = blockIdx.x * 128, n0 = blockIdx.y * 128;

  f32x4 acc[4][4];
  #pragma unroll
  for (int i = 0; i < 4; ++i)
    #pragma unroll
    for (int j = 0; j < 4; ++j) acc[i][j] = f32x4{0.f, 0.f, 0.f, 0.f};

  for (int k0 = 0; k0 < DM; k0 += 64) {
    __syncthreads();
    #pragma unroll
    for (int i = 0; i < 4; ++i) {
      int c = t + i * 256;            // 1024 chunks of 16B per tile
      int row = c >> 3;               // 0..127
      int cc = (c & 7) ^ (row & 7);   // inverse swizzle on the GLOBAL side
      async_copy16(xb + (size_t)(m0 + row) * DM + k0 + cc * 8, As + c * 16);
      async_copy16(wt + (size_t)(n0 + row) * DM + k0 + cc * 8, Bs + c * 16);
    }
    __syncthreads();  // barrier drains vmcnt -> tiles ready

    bf16x8 af[2][4], bfr[2][4];
    #pragma unroll
    for (int kk = 0; kk < 2; ++kk) {
      #pragma unroll
      for (int i = 0; i < 4; ++i) {
        int ra = wm + i * 16 + lr;
        af[kk][i] = *(const bf16x8*)(As + ((ra * 128 + kk * 64 + g * 16) ^ ((ra & 7) << 4)));
        int rb = wn + i * 16 + lr;
        bfr[kk][i] = *(const bf16x8*)(Bs + ((rb * 128 + kk * 64 + g * 16) ^ ((rb & 7) << 4)));
      }
    }
    #pragma unroll
    for (int kk = 0; kk < 2; ++kk)
      #pragma unroll
      for (int mi = 0; mi < 4; ++mi)
        #pragma unroll
        for (int ni = 0; ni < 4; ++ni)
          acc[mi][ni] = __builtin_amdgcn_mfma_f32_16x16x32_bf16(
              af[kk][mi], bfr[kk][ni], acc[mi][ni], 0, 0, 0);
  }

  // epilogue: +bias, route column n -> (head, q/k/v, d); V stored transposed [bh][d][s]
  const float QSC = 0.18033688011112042f;  // 1/sqrt(64) * log2(e), folded into Q
  #pragma unroll
  for (int ni = 0; ni < 4; ++ni) {
    int n = n0 + wn + ni * 16 + lr;
    float bv = bias[n];
    int h = n / 192;
    int rr = n % 192;
    int typ = rr >> 6;
    int d = rr & 63;
    #pragma unroll
    for (int mi = 0; mi < 4; ++mi) {
      #pragma unroll
      for (int r = 0; r < 4; ++r) {
        int m = m0 + wm + mi * 16 + g * 4 + r;   // C row = (lane>>4)*4+reg (verified layout)
        int b = m >> 11, s = m & 2047;
        int bh = b * NH + h;
        float v = acc[mi][ni][r] + bv;
        if (typ == 0)      Qb[((size_t)bh * S_LEN + s) * HD + d] = f2bf(v * QSC);
        else if (typ == 1) Kb[((size_t)bh * S_LEN + s) * HD + d] = f2bf(v);
        else               Vt[((size_t)bh * HD + d) * S_LEN + s] = f2bf(v);
      }
    }
  }
}

// ---------------- flash attention: swapped QK^T, lane-local softmax ----------------
// 4 waves x 16 q rows, KVBLK=64, double-buffered K/V, one barrier per tile.
// S^T = mfma(kf, qf): lane holds q=lane&15, keys 16*ni+4*g+r  -> softmax in-register.
// O^T = mfma(vf, pf): C col = q = lane&15 -> rescale is lane-uniform scalar.
__global__ __launch_bounds__(256) void attn_kernel(
    const unsigned short* __restrict__ Qb, const unsigned short* __restrict__ Kb,
    const unsigned short* __restrict__ Vt, float* __restrict__ out) {
  __shared__ __align__(16) unsigned char Ks[2][64 * 128];   // K tile [64 keys][64 d]
  __shared__ __align__(16) unsigned char Vs[2][64 * 128];   // V^T tile [64 d][64 j]
  __shared__ __align__(16) unsigned char Ps[4][16 * 128];   // per-wave P [16 q][64 j]
  const int t = threadIdx.x;
  const int lane = t & 63;
  const int wave = t >> 6;
  const int lr = lane & 15, g = lane >> 4;
  const int bh = blockIdx.y;
  const int q0 = blockIdx.x * 64 + wave * 16;

  const unsigned short* Qbh = Qb + (size_t)bh * S_LEN * HD;
  const unsigned short* Kbh = Kb + (size_t)bh * S_LEN * HD;
  const unsigned short* Vbh = Vt + (size_t)bh * HD * S_LEN;

  bf16x8 qf[2];  // Q fragment (pre-scaled by 1/8*log2e at GEMM epilogue)
  #pragma unroll
  for (int kk = 0; kk < 2; ++kk)
    qf[kk] = *(const bf16x8*)(Qbh + (size_t)(q0 + lr) * HD + kk * 32 + g * 8);

  float m = -1e30f, lsum = 0.f;
  f32x4 oacc[4];
  #pragma unroll
  for (int di = 0; di < 4; ++di) oacc[di] = f32x4{0.f, 0.f, 0.f, 0.f};

  auto stage = [&](int kt, int buf) {
    #pragma unroll
    for (int i = 0; i < 2; ++i) {
      int c = t + i * 256;            // 512 chunks per tile
      int row = c >> 3;               // 0..63
      int cc = (c & 7) ^ (row & 7);   // inverse swizzle on global side
      async_copy16(Kbh + (size_t)(kt * 64 + row) * HD + cc * 8, &Ks[buf][c * 16]);
      async_copy16(Vbh + (size_t)row * S_LEN + kt * 64 + cc * 8, &Vs[buf][c * 16]);
    }
  };

  int cur = 0;
  stage(0, 0);
  __syncthreads();  // drains vmcnt -> tile 0 ready

  for (int kt = 0; kt < S_LEN / 64; ++kt) {
    if (kt < S_LEN / 64 - 1) stage(kt + 1, cur ^ 1);  // prefetch overlaps compute

    // S^T = K·Q^T (64 keys x 16 q): lane q=lr, key = 16*ni + 4*g + r
    f32x4 sacc[4];
    #pragma unroll
    for (int ni = 0; ni < 4; ++ni) {
      sacc[ni] = f32x4{0.f, 0.f, 0.f, 0.f};
      #pragma unroll
      for (int kk = 0; kk < 2; ++kk) {
        int r = ni * 16 + lr;
        bf16x8 kf = *(const bf16x8*)(&Ks[cur][(r * 128 + kk * 64 + g * 16) ^ ((r & 7) << 4)]);
        sacc[ni] = __builtin_amdgcn_mfma_f32_16x16x32_bf16(kf, qf[kk], sacc[ni], 0, 0, 0);
      }
    }

    // lane-local online softmax over 16 values (row lives in lanes lr, lr+16, lr+32, lr+48)
    float tm = fmaxf(
        fmaxf(fmaxf(fmaxf(sacc[0][0], sacc[0][1]), fmaxf(sacc[0][2], sacc[0][3])),
              fmaxf(fmaxf(sacc[1][0], sacc[1][1]), fmaxf(sacc[1][2], sacc[1][3]))),
        fmaxf(fmaxf(fmaxf(sacc[2][0], sacc[2][1]), fmaxf(sacc[2][2], sacc[2][3])),
              fmaxf(fmaxf(sacc[3][0], sacc[3][1]), fmaxf(sacc[3][2], sacc[3][3]))));
    tm = fmaxf(tm, __shfl_xor(tm, 16));
    tm = fmaxf(tm, __shfl_xor(tm, 32));
    float mn = fmaxf(m, tm);
    float alpha = exp2f(m - mn);
    m = mn;

    unsigned char* Pw = Ps[wave];
    float ps = 0.f;
    #pragma unroll
    for (int ni = 0; ni < 4; ++ni) {
      float p0 = exp2f(sacc[ni][0] - mn);
      float p1 = exp2f(sacc[ni][1] - mn);
      float p2 = exp2f(sacc[ni][2] - mn);
      float p3 = exp2f(sacc[ni][3] - mn);
      ps += (p0 + p1) + (p2 + p3);
      u32x2 w;
      w[0] = (unsigned int)f2bf(p0) | ((unsigned int)f2bf(p1) << 16);
      w[1] = (unsigned int)f2bf(p2) | ((unsigned int)f2bf(p3) << 16);
      // P[q=lr][key=16ni+4g+r], linear byte = lr*128 + ni*32 + g*8, row-swizzled
      *(u32x2*)(Pw + ((lr * 128 + ni * 32 + g * 8) ^ ((lr & 7) << 4))) = w;
    }
    ps += __shfl_xor(ps, 16);
    ps += __shfl_xor(ps, 32);
    lsum = lsum * alpha + ps;
    #pragma unroll
    for (int di = 0; di < 4; ++di) oacc[di] *= alpha;

    // drain the wave-local P ds_writes before reading them back
    asm volatile("s_waitcnt lgkmcnt(0)" ::: "memory");
    __builtin_amdgcn_sched_barrier(0);

    // O^T += V^T·P^T : A = V^T rows (d, keys contig), B = P rows (q, keys contig)
    bf16x8 pf[2];
    #pragma unroll
    for (int kk = 0; kk < 2; ++kk)
      pf[kk] = *(const bf16x8*)(Pw + ((lr * 128 + kk * 64 + g * 16) ^ ((lr & 7) << 4)));
    #pragma unroll
    for (int di = 0; di < 4; ++di) {
      #pragma unroll
      for (int kk = 0; kk < 2; ++kk) {
        int rv = di * 16 + lr;
        bf16x8 vf = *(const bf16x8*)(&Vs[cur][(rv * 128 + kk * 64 + g * 16) ^ ((rv & 7) << 4)]);
        oacc[di] = __builtin_amdgcn_mfma_f32_16x16x32_bf16(vf, pf[kk], oacc[di], 0, 0, 0);
      }
    }

    __syncthreads();  // all reads of both buffers done; prefetched tile landed
    cur ^= 1;
  }

  // normalize + write: oacc[di][r] = O[q=lr][d = di*16 + 4g + r]
  float inv = 1.0f / lsum;
  float* outp = out + ((size_t)bh * S_LEN + q0 + lr) * HD;
  #pragma unroll
  for (int di = 0; di < 4; ++di) {
    f32x4 o = oacc[di] * inv;
    *(f32x4*)(outp + di * 16 + g * 4) = o;
  }
}

extern "C" void kernel_launch(void* const* d_in, const int* in_sizes, int n_in,
                              void* d_out, int out_size, void* d_ws, size_t ws_size,
                              hipStream_t stream) {
  const float* x    = (const float*)d_in[0];
  const float* W    = (const float*)d_in[1];
  const float* bias = (const float*)d_in[2];
  float* out = (float*)d_out;

  // workspace partition (bf16 everywhere): ~38 MB total
  unsigned short* xb = (unsigned short*)d_ws;
  unsigned short* wt = xb + (size_t)MROWS * DM;
  unsigned short* Qb = wt + (size_t)NQKV * DM;
  unsigned short* Kb = Qb + (size_t)NBH * S_LEN * HD;
  unsigned short* Vt = Kb + (size_t)NBH * S_LEN * HD;

  cast_x_kernel<<<(MROWS * DM) / (256 * 8), 256, 0, stream>>>(x, xb);
  transpose_w_kernel<<<dim3(NQKV / 32, DM / 32), dim3(32, 8), 0, stream>>>(W, wt);
  qkv_gemm_kernel<<<dim3(MROWS / 128, NQKV / 128), 256, 0, stream>>>(xb, wt, bias, Qb, Kb, Vt);
  attn_kernel<<<dim3(S_LEN / 64, NBH), 256, 0, stream>>>(Qb, Kb, Vt, out);
}

// Round 3
// 138.052 us; speedup vs baseline: 1.3321x; 1.2164x over previous
//
#include <hip/hip_runtime.h>
#include <stdint.h>
#include <stddef.h>

#define S_LEN 2048
#define NH 16
#define HD 64          // head dim
#define DM 1024        // model dim
#define NQKV 3072      // 3*DM
#define MROWS 4096     // B*S
#define NBH 32         // B*NH

typedef float f32x4 __attribute__((ext_vector_type(4)));
typedef __bf16 bf16x8 __attribute__((ext_vector_type(8)));
typedef __bf16 bf16x4 __attribute__((ext_vector_type(4)));
typedef short short8_t __attribute__((ext_vector_type(8)));

// round-to-nearest-even fp32 -> bf16 (inputs finite)
__device__ __forceinline__ unsigned short f2bf(float f) {
  union { float f; unsigned int u; } v; v.f = f;
  unsigned int u = v.u;
  u += 0x7FFFu + ((u >> 16) & 1u);
  return (unsigned short)(u >> 16);
}

// async global->LDS, 16B per lane. LDS dest must be (wave-uniform base + lane*16).
__device__ __forceinline__ void async_copy16(const void* g, void* l) {
  __builtin_amdgcn_global_load_lds(
      (const __attribute__((address_space(1))) void*)g,
      (__attribute__((address_space(3))) void*)l, 16, 0, 0);
}

// ---------------- precast x -> bf16 ----------------
__global__ __launch_bounds__(256) void cast_x_kernel(const float* __restrict__ x,
                                                     unsigned short* __restrict__ xb) {
  size_t i = ((size_t)blockIdx.x * 256 + threadIdx.x) * 8;
  f32x4 a = *(const f32x4*)(x + i);
  f32x4 b = *(const f32x4*)(x + i + 4);
  union { unsigned short u[8]; short8_t v; } o;
  o.u[0] = f2bf(a[0]); o.u[1] = f2bf(a[1]); o.u[2] = f2bf(a[2]); o.u[3] = f2bf(a[3]);
  o.u[4] = f2bf(b[0]); o.u[5] = f2bf(b[1]); o.u[6] = f2bf(b[2]); o.u[7] = f2bf(b[3]);
  *(short8_t*)(xb + i) = o.v;
}

// ---------------- W[K][N] -> Wt[N][K] bf16 (LDS tile transpose) ----------------
__global__ __launch_bounds__(256) void transpose_w_kernel(const float* __restrict__ W,
                                                          unsigned short* __restrict__ wt) {
  __shared__ float tile[32][33];
  const int n0 = blockIdx.x * 32;
  const int k0 = blockIdx.y * 32;
  const int tx = threadIdx.x;   // 0..31
  const int ty = threadIdx.y;   // 0..7
  #pragma unroll
  for (int i = 0; i < 4; ++i)
    tile[ty + i * 8][tx] = W[(size_t)(k0 + ty + i * 8) * NQKV + n0 + tx];
  __syncthreads();
  #pragma unroll
  for (int i = 0; i < 4; ++i)
    wt[(size_t)(n0 + ty + i * 8) * DM + k0 + tx] = f2bf(tile[tx][ty + i * 8]);
}

// ---------------- QKV GEMM: [4096,1024] x [1024,3072] + bias -> Q,K,V^T (bf16) ----------------
// 128x128 tile, BK=64, 4 waves (2x2), 16x16x32 bf16 MFMA, global_load_lds staging
// with pre-swizzled source so LDS reads (^((row&7)<<4)) are bank-conflict-free.
// Q is pre-scaled by 1/sqrt(64)*log2(e) so attention works in exp2 domain directly.
__global__ __launch_bounds__(256) void qkv_gemm_kernel(
    const unsigned short* __restrict__ xb, const unsigned short* __restrict__ wt,
    const float* __restrict__ bias,
    unsigned short* __restrict__ Qb, unsigned short* __restrict__ Kb,
    unsigned short* __restrict__ Vt) {
  __shared__ __align__(16) unsigned char As[128 * 128];  // 128 rows x 64 bf16
  __shared__ __align__(16) unsigned char Bs[128 * 128];
  const int t = threadIdx.x;
  const int lane = t & 63;
  const int wave = t >> 6;
  const int wm = (wave >> 1) * 64, wn = (wave & 1) * 64;
  const int lr = lane & 15, g = lane >> 4;
  const int m0 = blockIdx.x * 128, n0 = blockIdx.y * 128;

  f32x4 acc[4][4];
  #pragma unroll
  for (int i = 0; i < 4; ++i)
    #pragma unroll
    for (int j = 0; j < 4; ++j) acc[i][j] = f32x4{0.f, 0.f, 0.f, 0.f};

  for (int k0 = 0; k0 < DM; k0 += 64) {
    __syncthreads();
    #pragma unroll
    for (int i = 0; i < 4; ++i) {
      int c = t + i * 256;            // 1024 chunks of 16B per tile
      int row = c >> 3;               // 0..127
      int cc = (c & 7) ^ (row & 7);   // inverse swizzle on the GLOBAL side
      async_copy16(xb + (size_t)(m0 + row) * DM + k0 + cc * 8, As + c * 16);
      async_copy16(wt + (size_t)(n0 + row) * DM + k0 + cc * 8, Bs + c * 16);
    }
    __syncthreads();  // barrier drains vmcnt -> tiles ready

    bf16x8 af[2][4], bfr[2][4];
    #pragma unroll
    for (int kk = 0; kk < 2; ++kk) {
      #pragma unroll
      for (int i = 0; i < 4; ++i) {
        int ra = wm + i * 16 + lr;
        af[kk][i] = *(const bf16x8*)(As + ((ra * 128 + kk * 64 + g * 16) ^ ((ra & 7) << 4)));
        int rb = wn + i * 16 + lr;
        bfr[kk][i] = *(const bf16x8*)(Bs + ((rb * 128 + kk * 64 + g * 16) ^ ((rb & 7) << 4)));
      }
    }
    #pragma unroll
    for (int kk = 0; kk < 2; ++kk)
      #pragma unroll
      for (int mi = 0; mi < 4; ++mi)
        #pragma unroll
        for (int ni = 0; ni < 4; ++ni)
          acc[mi][ni] = __builtin_amdgcn_mfma_f32_16x16x32_bf16(
              af[kk][mi], bfr[kk][ni], acc[mi][ni], 0, 0, 0);
  }

  // epilogue: +bias, route column n -> (head, q/k/v, d); V stored transposed [bh][d][s]
  const float QSC = 0.18033688011112042f;  // 1/sqrt(64) * log2(e), folded into Q
  #pragma unroll
  for (int ni = 0; ni < 4; ++ni) {
    int n = n0 + wn + ni * 16 + lr;
    float bv = bias[n];
    int h = n / 192;
    int rr = n % 192;
    int typ = rr >> 6;
    int d = rr & 63;
    #pragma unroll
    for (int mi = 0; mi < 4; ++mi) {
      #pragma unroll
      for (int r = 0; r < 4; ++r) {
        int m = m0 + wm + mi * 16 + g * 4 + r;   // C row = (lane>>4)*4+reg (verified layout)
        int b = m >> 11, s = m & 2047;
        int bh = b * NH + h;
        float v = acc[mi][ni][r] + bv;
        if (typ == 0)      Qb[((size_t)bh * S_LEN + s) * HD + d] = f2bf(v * QSC);
        else if (typ == 1) Kb[((size_t)bh * S_LEN + s) * HD + d] = f2bf(v);
        else               Vt[((size_t)bh * HD + d) * S_LEN + s] = f2bf(v);
      }
    }
  }
}

// ---------------- flash attention: swapped QK^T, lane-local softmax ----------------
// 4 waves x 16 q rows, KVBLK=64, double-buffered K/V with STATIC buffer indexing
// (kt-loop unrolled x2) so every swizzled LDS address is loop-invariant.
// S^T = mfma(kf, qf): lane holds q=lane&15, keys 16*ni+4*g+r -> softmax in-register.
// O^T = mfma(vf, pf): C col = q = lane&15 -> rescale is lane-uniform scalar.
// Defer-max (THR=8, exp2 domain): skip rescale when max didn't grow much.
__global__ __launch_bounds__(256) void attn_kernel(
    const unsigned short* __restrict__ Qb, const unsigned short* __restrict__ Kb,
    const unsigned short* __restrict__ Vt, float* __restrict__ out) {
  __shared__ __align__(16) unsigned char Ks[2][64 * 128];   // K tile [64 keys][64 d]
  __shared__ __align__(16) unsigned char Vs[2][64 * 128];   // V^T tile [64 d][64 j]
  __shared__ __align__(16) unsigned char Ps[4][16 * 128];   // per-wave P [16 q][64 j]
  const int t = threadIdx.x;
  const int lane = t & 63;
  const int wave = t >> 6;
  const int lr = lane & 15, g = lane >> 4;
  const int bh = blockIdx.y;
  const int q0 = blockIdx.x * 64 + wave * 16;

  const unsigned short* Qbh = Qb + (size_t)bh * S_LEN * HD;
  const unsigned short* Kbh = Kb + (size_t)bh * S_LEN * HD;
  const unsigned short* Vbh = Vt + (size_t)bh * HD * S_LEN;

  bf16x8 qf[2];  // Q fragment (pre-scaled by 1/8*log2e at GEMM epilogue)
  #pragma unroll
  for (int kk = 0; kk < 2; ++kk)
    qf[kk] = *(const bf16x8*)(Qbh + (size_t)(q0 + lr) * HD + kk * 32 + g * 8);

  // ---- loop-invariant swizzled LDS offsets (live in VGPRs across the loop) ----
  int kvOff[4][2];                      // K and V share: row = i*16+lr
  #pragma unroll
  for (int i = 0; i < 4; ++i)
    #pragma unroll
    for (int kk = 0; kk < 2; ++kk) {
      int r = i * 16 + lr;
      kvOff[i][kk] = (r * 128 + kk * 64 + g * 16) ^ ((r & 7) << 4);
    }
  unsigned char* const Pw = Ps[wave];
  int pWr[4];                           // P write: row lr, keys ni*16+4g+{0..3}
  #pragma unroll
  for (int ni = 0; ni < 4; ++ni)
    pWr[ni] = (lr * 128 + ni * 32 + g * 8) ^ ((lr & 7) << 4);
  // P read offsets == kvOff[0][kk] (row = lr)

  // staging: per-lane source offsets (elements) and LDS chunk indices
  int c0 = t, c1 = t + 256;
  int row0 = c0 >> 3, row1 = c1 >> 3;
  int cc0 = (c0 & 7) ^ (row0 & 7), cc1 = (c1 & 7) ^ (row1 & 7);
  const int kGO0 = row0 * HD + cc0 * 8, kGO1 = row1 * HD + cc1 * 8;
  const int vGO0 = row0 * S_LEN + cc0 * 8, vGO1 = row1 * S_LEN + cc1 * 8;

  float m = -1e30f, lsum = 0.f;
  f32x4 oacc[4];
  #pragma unroll
  for (int di = 0; di < 4; ++di) oacc[di] = f32x4{0.f, 0.f, 0.f, 0.f};

  auto stage = [&](int kt, int buf) __attribute__((always_inline)) {
    const unsigned short* kp = Kbh + (size_t)kt * (64 * HD);
    const unsigned short* vp = Vbh + kt * 64;
    async_copy16(kp + kGO0, &Ks[buf][c0 * 16]);
    async_copy16(vp + vGO0, &Vs[buf][c0 * 16]);
    async_copy16(kp + kGO1, &Ks[buf][c1 * 16]);
    async_copy16(vp + vGO1, &Vs[buf][c1 * 16]);
  };

  auto compute = [&](int buf) __attribute__((always_inline)) {
    // S^T = K·Q^T (64 keys x 16 q): lane q=lr, key = 16*ni + 4*g + r
    f32x4 sacc[4];
    __builtin_amdgcn_s_setprio(1);
    #pragma unroll
    for (int ni = 0; ni < 4; ++ni) {
      sacc[ni] = f32x4{0.f, 0.f, 0.f, 0.f};
      #pragma unroll
      for (int kk = 0; kk < 2; ++kk) {
        bf16x8 kf = *(const bf16x8*)(&Ks[buf][kvOff[ni][kk]]);
        sacc[ni] = __builtin_amdgcn_mfma_f32_16x16x32_bf16(kf, qf[kk], sacc[ni], 0, 0, 0);
      }
    }
    __builtin_amdgcn_s_setprio(0);

    // lane-local online softmax (row lives in lanes lr, lr+16, lr+32, lr+48)
    float tm = fmaxf(
        fmaxf(fmaxf(fmaxf(sacc[0][0], sacc[0][1]), fmaxf(sacc[0][2], sacc[0][3])),
              fmaxf(fmaxf(sacc[1][0], sacc[1][1]), fmaxf(sacc[1][2], sacc[1][3]))),
        fmaxf(fmaxf(fmaxf(sacc[2][0], sacc[2][1]), fmaxf(sacc[2][2], sacc[2][3])),
              fmaxf(fmaxf(sacc[3][0], sacc[3][1]), fmaxf(sacc[3][2], sacc[3][3]))));
    tm = fmaxf(tm, __shfl_xor(tm, 16));
    tm = fmaxf(tm, __shfl_xor(tm, 32));
    if (!__all(tm <= m + 8.f)) {        // defer-max: rescale only on real growth
      float mn = fmaxf(m, tm);
      float alpha = exp2f(m - mn);
      m = mn;
      lsum *= alpha;
      #pragma unroll
      for (int di = 0; di < 4; ++di) oacc[di] *= alpha;
    }

    float ps = 0.f;
    #pragma unroll
    for (int ni = 0; ni < 4; ++ni) {
      float p0 = exp2f(sacc[ni][0] - m);
      float p1 = exp2f(sacc[ni][1] - m);
      float p2 = exp2f(sacc[ni][2] - m);
      float p3 = exp2f(sacc[ni][3] - m);
      ps += (p0 + p1) + (p2 + p3);
      bf16x4 w;                          // compiler emits v_cvt_pk_bf16_f32 pairs
      w[0] = (__bf16)p0; w[1] = (__bf16)p1; w[2] = (__bf16)p2; w[3] = (__bf16)p3;
      *(bf16x4*)(Pw + pWr[ni]) = w;
    }
    ps += __shfl_xor(ps, 16);
    ps += __shfl_xor(ps, 32);
    lsum += ps;

    // drain the wave-local P ds_writes before reading them back
    asm volatile("s_waitcnt lgkmcnt(0)" ::: "memory");
    __builtin_amdgcn_sched_barrier(0);

    // O^T += V^T·P^T : A = V^T rows (d, keys contig), B = P rows (q, keys contig)
    bf16x8 pf[2];
    #pragma unroll
    for (int kk = 0; kk < 2; ++kk)
      pf[kk] = *(const bf16x8*)(Pw + kvOff[0][kk]);
    __builtin_amdgcn_s_setprio(1);
    #pragma unroll
    for (int di = 0; di < 4; ++di) {
      #pragma unroll
      for (int kk = 0; kk < 2; ++kk) {
        bf16x8 vf = *(const bf16x8*)(&Vs[buf][kvOff[di][kk]]);
        oacc[di] = __builtin_amdgcn_mfma_f32_16x16x32_bf16(vf, pf[kk], oacc[di], 0, 0, 0);
      }
    }
    __builtin_amdgcn_s_setprio(0);
  };

  stage(0, 0);
  __syncthreads();  // drains vmcnt -> tile 0 ready

  for (int kt = 0; kt < S_LEN / 64; kt += 2) {
    stage(kt + 1, 1);                    // prefetch overlaps compute (kt+1 <= 31)
    compute(0);
    __syncthreads();                     // buf1 landed; buf0 reads done
    if (kt + 2 < S_LEN / 64) stage(kt + 2, 0);
    compute(1);
    __syncthreads();                     // buf0 landed; buf1 reads done
  }

  // normalize + write: oacc[di][r] = O[q=lr][d = di*16 + 4g + r]
  float inv = 1.0f / lsum;
  float* outp = out + ((size_t)bh * S_LEN + q0 + lr) * HD;
  #pragma unroll
  for (int di = 0; di < 4; ++di) {
    f32x4 o = oacc[di] * inv;
    *(f32x4*)(outp + di * 16 + g * 4) = o;
  }
}

extern "C" void kernel_launch(void* const* d_in, const int* in_sizes, int n_in,
                              void* d_out, int out_size, void* d_ws, size_t ws_size,
                              hipStream_t stream) {
  const float* x    = (const float*)d_in[0];
  const float* W    = (const float*)d_in[1];
  const float* bias = (const float*)d_in[2];
  float* out = (float*)d_out;

  // workspace partition (bf16 everywhere): ~38 MB total
  unsigned short* xb = (unsigned short*)d_ws;
  unsigned short* wt = xb + (size_t)MROWS * DM;
  unsigned short* Qb = wt + (size_t)NQKV * DM;
  unsigned short* Kb = Qb + (size_t)NBH * S_LEN * HD;
  unsigned short* Vt = Kb + (size_t)NBH * S_LEN * HD;

  cast_x_kernel<<<(MROWS * DM) / (256 * 8), 256, 0, stream>>>(x, xb);
  transpose_w_kernel<<<dim3(NQKV / 32, DM / 32), dim3(32, 8), 0, stream>>>(W, wt);
  qkv_gemm_kernel<<<dim3(MROWS / 128, NQKV / 128), 256, 0, stream>>>(xb, wt, bias, Qb, Kb, Vt);
  attn_kernel<<<dim3(S_LEN / 64, NBH), 256, 0, stream>>>(Qb, Kb, Vt, out);
}